// Round 1
// baseline (396.318 us; speedup 1.0000x reference)
//
#include <hip/hip_runtime.h>
#include <hip/hip_bf16.h>

// Problem constants
constexpr int B_ = 4, L_ = 4096, D_ = 1024, INNER_ = 2048;
constexpr int M_ = B_ * L_;       // 16384 rows
constexpr int N1_ = 2 * INNER_;   // 4096 (W_in output cols)

typedef __attribute__((ext_vector_type(4))) float f32x4;
typedef __attribute__((ext_vector_type(8))) short short8;

#define DEV static __device__ __forceinline__

DEV short f2bfs(float f) {
  __hip_bfloat16 h = __float2bfloat16(f);
  return __builtin_bit_cast(short, h);
}
DEV float bfs2f(short s) {
  unsigned int u = ((unsigned int)(unsigned short)s) << 16;
  return __builtin_bit_cast(float, u);
}

DEV void gload_lds16(const void* g, void* l) {
  __builtin_amdgcn_global_load_lds(
      (const __attribute__((address_space(1))) unsigned int*)g,
      (__attribute__((address_space(3))) unsigned int*)l,
      16, 0, 0);
}

// ---------------- fp32 -> bf16 convert (vectorized) ----------------
__global__ void k_cvt(const float4* __restrict__ in, short4* __restrict__ out, int n4) {
  int i = blockIdx.x * blockDim.x + threadIdx.x;
  if (i >= n4) return;
  float4 v = in[i];
  short4 o;
  o.x = f2bfs(v.x); o.y = f2bfs(v.y); o.z = f2bfs(v.z); o.w = f2bfs(v.w);
  out[i] = o;
}

// ---------------- fp32 [R][C] -> bf16 transposed [C][R] ----------------
__global__ void k_transpose_cvt(const float* __restrict__ W, short* __restrict__ Wt,
                                int R, int C) {
  __shared__ short tile[32][33];
  int tx = threadIdx.x & 31;
  int ty = threadIdx.x >> 5;          // 0..7
  int c0 = blockIdx.x * 32;
  int r0 = blockIdx.y * 32;
#pragma unroll
  for (int i = 0; i < 32; i += 8)
    tile[ty + i][tx] = f2bfs(W[(size_t)(r0 + ty + i) * C + (c0 + tx)]);
  __syncthreads();
#pragma unroll
  for (int i = 0; i < 32; i += 8)
    Wt[(size_t)(c0 + ty + i) * R + (r0 + tx)] = tile[tx][ty + i];
}

// ---------------- GEMM1 + GLU epilogue ----------------
// A  : Xb   [M_,1024] bf16 row-major
// Bt : WinT [4096,1024] bf16 (n-major, k-minor)
// G  : [M_, 2048] bf16 ; G = a * sigmoid(g), a=H[:, n], g=H[:, n+2048]
__global__ __launch_bounds__(256, 2) void k_gemm1_glu(
    const short* __restrict__ A, const short* __restrict__ Bt,
    short* __restrict__ G) {
  constexpr int K = 1024, BK = 32, NK = K / BK;
  __shared__ short sA[128 * 32];
  __shared__ short sBa[128 * 32];
  __shared__ short sBg[128 * 32];

  const int tid = threadIdx.x;
  const int wid = tid >> 6;
  const int lane = tid & 63;
  const int m0 = blockIdx.x * 128;
  const int n0 = blockIdx.y * 128;

  const int srow = wid * 32 + (lane >> 2);  // staging row (+ j*16)
  const int scol = (lane & 3) * 8;          // staging col element

  const int wr = wid >> 1, wc = wid & 1;
  const int l16 = lane & 15, kg = lane >> 4;

  const f32x4 vzero = {0.f, 0.f, 0.f, 0.f};
  f32x4 acc_a[4][4], acc_g[4][4];
#pragma unroll
  for (int m = 0; m < 4; ++m)
#pragma unroll
    for (int n = 0; n < 4; ++n) { acc_a[m][n] = vzero; acc_g[m][n] = vzero; }

  for (int kt = 0; kt < NK; ++kt) {
    const int k0 = kt * BK;
#pragma unroll
    for (int j = 0; j < 2; ++j) {
      const int r = srow + j * 16;
      gload_lds16(A + (size_t)(m0 + r) * K + k0 + scol, &sA[(wid * 32 + j * 16) * 32]);
      gload_lds16(Bt + (size_t)(n0 + r) * K + k0 + scol, &sBa[(wid * 32 + j * 16) * 32]);
      gload_lds16(Bt + (size_t)(n0 + 2048 + r) * K + k0 + scol, &sBg[(wid * 32 + j * 16) * 32]);
    }
    __syncthreads();

    short8 af[4], ba[4], bg[4];
#pragma unroll
    for (int m = 0; m < 4; ++m)
      af[m] = *(const short8*)&sA[(wr * 64 + m * 16 + l16) * 32 + kg * 8];
#pragma unroll
    for (int n = 0; n < 4; ++n) {
      ba[n] = *(const short8*)&sBa[(wc * 64 + n * 16 + l16) * 32 + kg * 8];
      bg[n] = *(const short8*)&sBg[(wc * 64 + n * 16 + l16) * 32 + kg * 8];
    }
#pragma unroll
    for (int m = 0; m < 4; ++m)
#pragma unroll
      for (int n = 0; n < 4; ++n) {
        acc_a[m][n] = __builtin_amdgcn_mfma_f32_16x16x32_bf16(af[m], ba[n], acc_a[m][n], 0, 0, 0);
        acc_g[m][n] = __builtin_amdgcn_mfma_f32_16x16x32_bf16(af[m], bg[n], acc_g[m][n], 0, 0, 0);
      }
    __syncthreads();
  }

  // epilogue: G = a * sigmoid(g); C/D map: col=lane&15, row=(lane>>4)*4+r
#pragma unroll
  for (int m = 0; m < 4; ++m) {
    const int row0 = m0 + wr * 64 + m * 16 + (lane >> 4) * 4;
#pragma unroll
    for (int n = 0; n < 4; ++n) {
      const int col = n0 + wc * 64 + n * 16 + l16;
#pragma unroll
      for (int r = 0; r < 4; ++r) {
        float a = acc_a[m][n][r];
        float g = acc_g[m][n][r];
        float v = a / (1.f + __expf(-g));
        G[(size_t)(row0 + r) * 2048 + col] = f2bfs(v);
      }
    }
  }
}

// ---------------- depthwise causal conv(K=4) + bias + SiLU ----------------
// G: [B_*L_, 2048] bf16 -> Y same shape. Per-batch left zero-pad of 3.
__global__ void k_conv_silu(const short* __restrict__ G, const float* __restrict__ w,
                            const float* __restrict__ bias, short* __restrict__ Y) {
  const int t = threadIdx.x;       // 0..255
  const int c0 = t * 8;            // 8 channels per thread
  const int b = blockIdx.y;
  const int l0 = blockIdx.x * 16;  // 16 rows per thread
  const size_t base = ((size_t)b * L_) * INNER_ + c0;

  float wv[4][8], bv[8];
#pragma unroll
  for (int j = 0; j < 8; ++j) bv[j] = bias[c0 + j];
#pragma unroll
  for (int k = 0; k < 4; ++k)
#pragma unroll
    for (int j = 0; j < 8; ++j) wv[k][j] = w[(c0 + j) * 4 + k];

  float h[3][8];
#pragma unroll
  for (int p = 0; p < 3; ++p) {
    const int l = l0 - 3 + p;
    if (l < 0) {
#pragma unroll
      for (int j = 0; j < 8; ++j) h[p][j] = 0.f;
    } else {
      short8 v = *(const short8*)(G + base + (size_t)l * INNER_);
#pragma unroll
      for (int j = 0; j < 8; ++j) h[p][j] = bfs2f(v[j]);
    }
  }

  for (int i = 0; i < 16; ++i) {
    const int l = l0 + i;
    short8 v = *(const short8*)(G + base + (size_t)l * INNER_);
    short8 o;
#pragma unroll
    for (int j = 0; j < 8; ++j) {
      float g0 = bfs2f(v[j]);
      float y = bv[j] + wv[0][j] * h[0][j] + wv[1][j] * h[1][j] + wv[2][j] * h[2][j] + wv[3][j] * g0;
      y = y / (1.f + __expf(-y));  // SiLU
      o[j] = f2bfs(y);
      h[0][j] = h[1][j]; h[1][j] = h[2][j]; h[2][j] = g0;
    }
    *(short8*)(Y + base + (size_t)l * INNER_) = o;
  }
}

// ---------------- GEMM2 (plain, fp32 out) ----------------
// A: Y [M_,2048] bf16 ; Bt: WoutT [1024,2048] bf16 ; Out: [M_,1024] fp32
__global__ __launch_bounds__(256, 2) void k_gemm2(
    const short* __restrict__ A, const short* __restrict__ Bt,
    float* __restrict__ Out) {
  constexpr int K = 2048, BK = 32, NK = K / BK;
  __shared__ short sA[128 * 32];
  __shared__ short sB[128 * 32];

  const int tid = threadIdx.x;
  const int wid = tid >> 6;
  const int lane = tid & 63;
  const int m0 = blockIdx.x * 128;
  const int n0 = blockIdx.y * 128;

  const int srow = wid * 32 + (lane >> 2);
  const int scol = (lane & 3) * 8;

  const int wr = wid >> 1, wc = wid & 1;
  const int l16 = lane & 15, kg = lane >> 4;

  const f32x4 vzero = {0.f, 0.f, 0.f, 0.f};
  f32x4 acc[4][4];
#pragma unroll
  for (int m = 0; m < 4; ++m)
#pragma unroll
    for (int n = 0; n < 4; ++n) acc[m][n] = vzero;

  for (int kt = 0; kt < NK; ++kt) {
    const int k0 = kt * BK;
#pragma unroll
    for (int j = 0; j < 2; ++j) {
      const int r = srow + j * 16;
      gload_lds16(A + (size_t)(m0 + r) * K + k0 + scol, &sA[(wid * 32 + j * 16) * 32]);
      gload_lds16(Bt + (size_t)(n0 + r) * K + k0 + scol, &sB[(wid * 32 + j * 16) * 32]);
    }
    __syncthreads();

    short8 af[4], bf[4];
#pragma unroll
    for (int m = 0; m < 4; ++m)
      af[m] = *(const short8*)&sA[(wr * 64 + m * 16 + l16) * 32 + kg * 8];
#pragma unroll
    for (int n = 0; n < 4; ++n)
      bf[n] = *(const short8*)&sB[(wc * 64 + n * 16 + l16) * 32 + kg * 8];
#pragma unroll
    for (int m = 0; m < 4; ++m)
#pragma unroll
      for (int n = 0; n < 4; ++n)
        acc[m][n] = __builtin_amdgcn_mfma_f32_16x16x32_bf16(af[m], bf[n], acc[m][n], 0, 0, 0);
    __syncthreads();
  }

#pragma unroll
  for (int m = 0; m < 4; ++m) {
    const int row0 = m0 + wr * 64 + m * 16 + (lane >> 4) * 4;
#pragma unroll
    for (int n = 0; n < 4; ++n) {
      const int col = n0 + wc * 64 + n * 16 + l16;
#pragma unroll
      for (int r = 0; r < 4; ++r)
        Out[(size_t)(row0 + r) * 1024 + col] = acc[m][n][r];
    }
  }
}

extern "C" void kernel_launch(void* const* d_in, const int* in_sizes, int n_in,
                              void* d_out, int out_size, void* d_ws, size_t ws_size,
                              hipStream_t stream) {
  (void)in_sizes; (void)n_in; (void)out_size; (void)ws_size;
  const float* x      = (const float*)d_in[0];
  const float* W_in   = (const float*)d_in[1];
  const float* conv_w = (const float*)d_in[2];
  const float* conv_b = (const float*)d_in[3];
  const float* W_out  = (const float*)d_in[4];
  float* out = (float*)d_out;

  char* ws = (char*)d_ws;
  size_t off = 0;
  auto alloc = [&](size_t bytes) {
    char* p = ws + off;
    off += (bytes + 255) & ~(size_t)255;
    return p;
  };
  short* Xb    = (short*)alloc((size_t)M_ * D_ * 2);       // 33.5 MB
  short* WinT  = (short*)alloc((size_t)N1_ * D_ * 2);      // 8.4 MB
  short* WoutT = (short*)alloc((size_t)D_ * INNER_ * 2);   // 4.2 MB
  short* G     = (short*)alloc((size_t)M_ * INNER_ * 2);   // 67 MB
  short* Y     = (short*)alloc((size_t)M_ * INNER_ * 2);   // 67 MB

  // Convert x to bf16
  k_cvt<<<(M_ * D_ / 4 + 255) / 256, 256, 0, stream>>>(
      (const float4*)x, (short4*)Xb, M_ * D_ / 4);
  // Transpose+convert weights: W_in [1024,4096] -> WinT [4096,1024]
  k_transpose_cvt<<<dim3(N1_ / 32, D_ / 32), 256, 0, stream>>>(W_in, WinT, D_, N1_);
  // W_out [2048,1024] -> WoutT [1024,2048]
  k_transpose_cvt<<<dim3(D_ / 32, INNER_ / 32), 256, 0, stream>>>(W_out, WoutT, INNER_, D_);

  // GEMM1 + GLU -> G
  k_gemm1_glu<<<dim3(M_ / 128, INNER_ / 128), 256, 0, stream>>>(Xb, WinT, G);
  // conv + SiLU -> Y
  k_conv_silu<<<dim3(L_ / 16, B_), 256, 0, stream>>>(G, conv_w, conv_b, Y);
  // GEMM2 -> out (fp32)
  k_gemm2<<<dim3(M_ / 128, D_ / 128), 256, 0, stream>>>(Y, WoutT, out);
}

// Round 2
// 395.112 us; speedup vs baseline: 1.0031x; 1.0031x over previous
//
#include <hip/hip_runtime.h>
#include <hip/hip_bf16.h>

// Problem constants
constexpr int B_ = 4, L_ = 4096, D_ = 1024, INNER_ = 2048;
constexpr int M_ = B_ * L_;       // 16384 rows
constexpr int N1_ = 2 * INNER_;   // 4096 (W_in output cols)

typedef __attribute__((ext_vector_type(4))) float f32x4;
typedef __attribute__((ext_vector_type(8))) short short8;

#define DEV static __device__ __forceinline__

DEV short f2bfs(float f) {
  __hip_bfloat16 h = __float2bfloat16(f);
  return __builtin_bit_cast(short, h);
}
DEV float bfs2f(short s) {
  unsigned int u = ((unsigned int)(unsigned short)s) << 16;
  return __builtin_bit_cast(float, u);
}

DEV void gload_lds16(const void* g, void* l) {
  __builtin_amdgcn_global_load_lds(
      (const __attribute__((address_space(1))) unsigned int*)g,
      (__attribute__((address_space(3))) unsigned int*)l,
      16, 0, 0);
}

// gfx9 s_waitcnt immediates: vmcnt[3:0]|expcnt<<4|lgkmcnt<<8|vmcnt[5:4]<<14
constexpr int VMW8 = 0x0F78;  // vmcnt(8), others no-wait
constexpr int VMW4 = 0x0F74;  // vmcnt(4)
constexpr int VMW0 = 0x0F70;  // vmcnt(0)

// ---------------- fp32 -> bf16 convert (vectorized) ----------------
__global__ void k_cvt(const float4* __restrict__ in, short4* __restrict__ out, int n4) {
  int i = blockIdx.x * blockDim.x + threadIdx.x;
  if (i >= n4) return;
  float4 v = in[i];
  short4 o;
  o.x = f2bfs(v.x); o.y = f2bfs(v.y); o.z = f2bfs(v.z); o.w = f2bfs(v.w);
  out[i] = o;
}

// ---------------- fp32 [R][C] -> bf16 transposed [C][R] ----------------
__global__ void k_transpose_cvt(const float* __restrict__ W, short* __restrict__ Wt,
                                int R, int C) {
  __shared__ short tile[32][33];
  int tx = threadIdx.x & 31;
  int ty = threadIdx.x >> 5;          // 0..7
  int c0 = blockIdx.x * 32;
  int r0 = blockIdx.y * 32;
#pragma unroll
  for (int i = 0; i < 32; i += 8)
    tile[ty + i][tx] = f2bfs(W[(size_t)(r0 + ty + i) * C + (c0 + tx)]);
  __syncthreads();
#pragma unroll
  for (int i = 0; i < 32; i += 8)
    Wt[(size_t)(c0 + ty + i) * R + (r0 + tx)] = tile[tx][ty + i];
}

// ---------------- Pipelined 256x256 GEMM (BK=32, 4-slot ring, counted vmcnt) ----
// A  : [M_, K] bf16 row-major
// Bt : [N, K] bf16 (n-major, k-minor)
// GLU=true : combined B rows [a 0-63][g 0-63][a 64-127][g 64-127] per 128-col
//            output block; epilogue writes OutBf = a*sigmoid(g), [M_,2048] bf16.
// GLU=false: plain 256-col output block; epilogue writes OutF fp32 [M_,1024].
//
// LDS slot (32 KB): [A tile 256x32 bf16 : 16KB][B tile 256x32 bf16 : 16KB]
// Swizzle (T2): 16B chunk index ch -> ch ^ ((ch>>3)&7)  (involution).
// Stage (T3/T4): tile t+3 staged during iter t; vmcnt(8) steady state.
template<int K, bool GLU>
__global__ __launch_bounds__(512, 2) void k_gemm_pipe(
    const short* __restrict__ A, const short* __restrict__ Bt,
    short* __restrict__ OutBf, float* __restrict__ OutF) {
  extern __shared__ char lds[];
  constexpr int NT = K / 32;
  const int tid = threadIdx.x;
  const int wid = tid >> 6, lane = tid & 63;
  const int l16 = lane & 15, kg = lane >> 4;
  const int wr = wid >> 1, wc = wid & 1;   // 4M x 2N wave grid

  // T1: bijective XCD swizzle (nwg % 8 == 0 for both instantiations)
  const int nwg = (int)gridDim.x;
  const int bid = (int)blockIdx.x;
  const int swz = (bid & 7) * (nwg >> 3) + (bid >> 3);
  const int bm = swz & 63;            // grid M = M_/256 = 64 for both
  const int bn = swz >> 6;
  const int m0 = bm * 256;

  // ---- per-thread stage descriptors (2 A-chunks + 2 B-chunks per K-tile) ----
  const short* pA[2];
  const short* pB[2];
  int ldsA[2], ldsB[2];
#pragma unroll
  for (int h = 0; h < 2; ++h) {
    int p = h * 512 + wid * 64 + lane;      // physical 16B chunk this lane fills
    int q = p ^ ((p >> 3) & 7);             // logical chunk (involution)
    int row = q >> 2, c = q & 3;            // 4 chunks per 64B row
    pA[h] = A + (size_t)(m0 + row) * K + c * 8;
    int gb;
    if constexpr (GLU) {
      // combined row -> Bt row: [a c0-63][g c0-63][a c64-127][g c64-127]
      gb = bn * 128 + ((row >> 7) << 6) + (row & 63) + (((row >> 6) & 1) ? 2048 : 0);
    } else {
      gb = bn * 256 + row;
    }
    pB[h] = Bt + (size_t)gb * K + c * 8;
    ldsA[h] = h * 8192 + wid * 1024;            // linear dest, wave-uniform
    ldsB[h] = 16384 + h * 8192 + wid * 1024;
  }

  // ---- ds_read fragment offsets (swizzled, loop-invariant) ----
  int offA[4], offB[8];
#pragma unroll
  for (int m = 0; m < 4; ++m) {
    int row = wr * 64 + m * 16 + l16;
    int ch = row * 4 + kg;
    offA[m] = (ch ^ ((ch >> 3) & 7)) * 16;
  }
#pragma unroll
  for (int n = 0; n < 8; ++n) {
    int row = wc * 128 + n * 16 + l16;
    int ch = row * 4 + kg;
    offB[n] = 16384 + (ch ^ ((ch >> 3) & 7)) * 16;
  }

  const f32x4 z = {0.f, 0.f, 0.f, 0.f};
  f32x4 acc[4][8];
#pragma unroll
  for (int m = 0; m < 4; ++m)
#pragma unroll
    for (int n = 0; n < 8; ++n) acc[m][n] = z;

  // ---- prologue: stage tiles 0..2 (tile-major issue order for vmcnt FIFO) ----
#pragma unroll
  for (int tt = 0; tt < 3; ++tt) {
    char* ws = lds + tt * 32768;
#pragma unroll
    for (int h = 0; h < 2; ++h) {
      gload_lds16(pA[h] + tt * 32, ws + ldsA[h]);
      gload_lds16(pB[h] + tt * 32, ws + ldsB[h]);
    }
  }
#pragma unroll
  for (int h = 0; h < 2; ++h) { pA[h] += 96; pB[h] += 96; }  // -> tile 3

  auto iter = [&](int t, bool do_stage) {
    __builtin_amdgcn_s_barrier();   // everyone's vmcnt wait done -> tile t ready
    char* slot = lds + (t & 3) * 32768;
    char* wsl  = lds + ((t + 3) & 3) * 32768;
    short8 af[4], bfr[4];
    // ---- phase 0: ds A(4)+B(0..3), stage A of t+3, MFMA n0..3 ----
#pragma unroll
    for (int m = 0; m < 4; ++m) af[m] = *(const short8*)(slot + offA[m]);
#pragma unroll
    for (int n = 0; n < 4; ++n) bfr[n] = *(const short8*)(slot + offB[n]);
    if (do_stage) {
      gload_lds16(pA[0], wsl + ldsA[0]);
      gload_lds16(pA[1], wsl + ldsA[1]);
    }
    __builtin_amdgcn_s_barrier();
    asm volatile("s_waitcnt lgkmcnt(0)" ::: "memory");
    __builtin_amdgcn_sched_barrier(0);
    __builtin_amdgcn_s_setprio(1);
#pragma unroll
    for (int m = 0; m < 4; ++m)
#pragma unroll
      for (int n = 0; n < 4; ++n)
        acc[m][n] = __builtin_amdgcn_mfma_f32_16x16x32_bf16(af[m], bfr[n], acc[m][n], 0, 0, 0);
    __builtin_amdgcn_s_setprio(0);
    __builtin_amdgcn_s_barrier();
    // ---- phase 1: ds B(4..7), stage B of t+3, MFMA n4..7 ----
#pragma unroll
    for (int n = 0; n < 4; ++n) bfr[n] = *(const short8*)(slot + offB[4 + n]);
    if (do_stage) {
      gload_lds16(pB[0], wsl + ldsB[0]);
      gload_lds16(pB[1], wsl + ldsB[1]);
      pA[0] += 32; pA[1] += 32; pB[0] += 32; pB[1] += 32;
    }
    __builtin_amdgcn_s_barrier();
    asm volatile("s_waitcnt lgkmcnt(0)" ::: "memory");
    __builtin_amdgcn_sched_barrier(0);
    __builtin_amdgcn_s_setprio(1);
#pragma unroll
    for (int m = 0; m < 4; ++m)
#pragma unroll
      for (int n = 0; n < 4; ++n)
        acc[m][4 + n] = __builtin_amdgcn_mfma_f32_16x16x32_bf16(af[m], bfr[n], acc[m][4 + n], 0, 0, 0);
    __builtin_amdgcn_s_setprio(0);
  };

  // main loop: stages tile t+3, counted vmcnt(8) — never drains to 0
  for (int t = 0; t < NT - 3; ++t) {
    __builtin_amdgcn_s_waitcnt(VMW8);
    iter(t, true);
  }
  __builtin_amdgcn_s_waitcnt(VMW8); iter(NT - 3, false);
  __builtin_amdgcn_s_waitcnt(VMW4); iter(NT - 2, false);
  __builtin_amdgcn_s_waitcnt(VMW0); iter(NT - 1, false);

  // ---- epilogue (C/D map: col=lane&15, row=(lane>>4)*4+r) ----
  const int r4 = (lane >> 4) * 4;
  if constexpr (GLU) {
#pragma unroll
    for (int m = 0; m < 4; ++m) {
      const int row = m0 + wr * 64 + m * 16 + r4;
#pragma unroll
      for (int n = 0; n < 4; ++n) {
        const int col = bn * 128 + wc * 64 + n * 16 + l16;
#pragma unroll
        for (int r = 0; r < 4; ++r) {
          float a = acc[m][n][r];
          float g = acc[m][4 + n][r];
          OutBf[(size_t)(row + r) * 2048 + col] = f2bfs(a / (1.f + __expf(-g)));
        }
      }
    }
  } else {
#pragma unroll
    for (int m = 0; m < 4; ++m) {
      const int row = m0 + wr * 64 + m * 16 + r4;
#pragma unroll
      for (int n = 0; n < 8; ++n) {
        const int col = bn * 256 + wc * 128 + n * 16 + l16;
#pragma unroll
        for (int r = 0; r < 4; ++r)
          OutF[(size_t)(row + r) * 1024 + col] = acc[m][n][r];
      }
    }
  }
}

// ---------------- depthwise causal conv(K=4) + bias + SiLU ----------------
__global__ void k_conv_silu(const short* __restrict__ G, const float* __restrict__ w,
                            const float* __restrict__ bias, short* __restrict__ Y) {
  const int t = threadIdx.x;       // 0..255
  const int c0 = t * 8;            // 8 channels per thread
  const int b = blockIdx.y;
  const int l0 = blockIdx.x * 16;  // 16 rows per thread
  const size_t base = ((size_t)b * L_) * INNER_ + c0;

  float wv[4][8], bv[8];
#pragma unroll
  for (int j = 0; j < 8; ++j) bv[j] = bias[c0 + j];
#pragma unroll
  for (int k = 0; k < 4; ++k)
#pragma unroll
    for (int j = 0; j < 8; ++j) wv[k][j] = w[(c0 + j) * 4 + k];

  float h[3][8];
#pragma unroll
  for (int p = 0; p < 3; ++p) {
    const int l = l0 - 3 + p;
    if (l < 0) {
#pragma unroll
      for (int j = 0; j < 8; ++j) h[p][j] = 0.f;
    } else {
      short8 v = *(const short8*)(G + base + (size_t)l * INNER_);
#pragma unroll
      for (int j = 0; j < 8; ++j) h[p][j] = bfs2f(v[j]);
    }
  }

  for (int i = 0; i < 16; ++i) {
    const int l = l0 + i;
    short8 v = *(const short8*)(G + base + (size_t)l * INNER_);
    short8 o;
#pragma unroll
    for (int j = 0; j < 8; ++j) {
      float g0 = bfs2f(v[j]);
      float y = bv[j] + wv[0][j] * h[0][j] + wv[1][j] * h[1][j] + wv[2][j] * h[2][j] + wv[3][j] * g0;
      y = y / (1.f + __expf(-y));  // SiLU
      o[j] = f2bfs(y);
      h[0][j] = h[1][j]; h[1][j] = h[2][j]; h[2][j] = g0;
    }
    *(short8*)(Y + base + (size_t)l * INNER_) = o;
  }
}

extern "C" void kernel_launch(void* const* d_in, const int* in_sizes, int n_in,
                              void* d_out, int out_size, void* d_ws, size_t ws_size,
                              hipStream_t stream) {
  (void)in_sizes; (void)n_in; (void)out_size; (void)ws_size;
  const float* x      = (const float*)d_in[0];
  const float* W_in   = (const float*)d_in[1];
  const float* conv_w = (const float*)d_in[2];
  const float* conv_b = (const float*)d_in[3];
  const float* W_out  = (const float*)d_in[4];
  float* out = (float*)d_out;

  char* ws = (char*)d_ws;
  size_t off = 0;
  auto alloc = [&](size_t bytes) {
    char* p = ws + off;
    off += (bytes + 255) & ~(size_t)255;
    return p;
  };
  short* Xb    = (short*)alloc((size_t)M_ * D_ * 2);       // 33.5 MB
  short* WinT  = (short*)alloc((size_t)N1_ * D_ * 2);      // 8.4 MB
  short* WoutT = (short*)alloc((size_t)D_ * INNER_ * 2);   // 4.2 MB
  short* G     = (short*)alloc((size_t)M_ * INNER_ * 2);   // 67 MB
  short* Y     = (short*)alloc((size_t)M_ * INNER_ * 2);   // 67 MB

  // allow 128 KiB dynamic LDS (idempotent; same work every call)
  hipFuncSetAttribute((const void*)k_gemm_pipe<1024, true>,
                      hipFuncAttributeMaxDynamicSharedMemorySize, 131072);
  hipFuncSetAttribute((const void*)k_gemm_pipe<2048, false>,
                      hipFuncAttributeMaxDynamicSharedMemorySize, 131072);

  // Convert x to bf16
  k_cvt<<<(M_ * D_ / 4 + 255) / 256, 256, 0, stream>>>(
      (const float4*)x, (short4*)Xb, M_ * D_ / 4);
  // Transpose+convert weights
  k_transpose_cvt<<<dim3(N1_ / 32, D_ / 32), 256, 0, stream>>>(W_in, WinT, D_, N1_);
  k_transpose_cvt<<<dim3(D_ / 32, INNER_ / 32), 256, 0, stream>>>(W_out, WoutT, INNER_, D_);

  // GEMM1 + GLU -> G   (grid: 64 M-blocks x 16 N-blocks)
  k_gemm_pipe<1024, true><<<1024, 512, 131072, stream>>>(Xb, WinT, G, nullptr);
  // conv + SiLU -> Y
  k_conv_silu<<<dim3(L_ / 16, B_), 256, 0, stream>>>(G, conv_w, conv_b, Y);
  // GEMM2 -> out (fp32)   (grid: 64 x 4)
  k_gemm_pipe<2048, false><<<256, 512, 131072, stream>>>(Y, WoutT, nullptr, out);
}

// Round 3
// 377.975 us; speedup vs baseline: 1.0485x; 1.0453x over previous
//
#include <hip/hip_runtime.h>
#include <hip/hip_bf16.h>

// Problem constants
constexpr int B_ = 4, L_ = 4096, D_ = 1024, INNER_ = 2048;
constexpr int M_ = B_ * L_;       // 16384 rows
constexpr int N1_ = 2 * INNER_;   // 4096 (W_in output cols)

typedef __attribute__((ext_vector_type(4))) float f32x4;
typedef __attribute__((ext_vector_type(8))) short short8;

#define DEV static __device__ __forceinline__

DEV short f2bfs(float f) {
  __hip_bfloat16 h = __float2bfloat16(f);
  return __builtin_bit_cast(short, h);
}
DEV float bfs2f(short s) {
  unsigned int u = ((unsigned int)(unsigned short)s) << 16;
  return __builtin_bit_cast(float, u);
}

DEV void gload_lds16(const void* g, void* l) {
  __builtin_amdgcn_global_load_lds(
      (const __attribute__((address_space(1))) unsigned int*)g,
      (__attribute__((address_space(3))) unsigned int*)l,
      16, 0, 0);
}

// gfx9 s_waitcnt immediates: vmcnt[3:0]|expcnt<<4|lgkmcnt<<8|vmcnt[5:4]<<14
constexpr int VMW8 = 0x0F78;  // vmcnt(8), others no-wait
constexpr int VMW4 = 0x0F74;  // vmcnt(4)
constexpr int VMW0 = 0x0F70;  // vmcnt(0)

// ---------------- fp32 -> bf16 convert (vectorized) ----------------
__global__ void k_cvt(const float4* __restrict__ in, short4* __restrict__ out, int n4) {
  int i = blockIdx.x * blockDim.x + threadIdx.x;
  if (i >= n4) return;
  float4 v = in[i];
  short4 o;
  o.x = f2bfs(v.x); o.y = f2bfs(v.y); o.z = f2bfs(v.z); o.w = f2bfs(v.w);
  out[i] = o;
}

// ---------------- fp32 [R][C] -> bf16 transposed [C][R] ----------------
__global__ void k_transpose_cvt(const float* __restrict__ W, short* __restrict__ Wt,
                                int R, int C) {
  __shared__ short tile[32][33];
  int tx = threadIdx.x & 31;
  int ty = threadIdx.x >> 5;          // 0..7
  int c0 = blockIdx.x * 32;
  int r0 = blockIdx.y * 32;
#pragma unroll
  for (int i = 0; i < 32; i += 8)
    tile[ty + i][tx] = f2bfs(W[(size_t)(r0 + ty + i) * C + (c0 + tx)]);
  __syncthreads();
#pragma unroll
  for (int i = 0; i < 32; i += 8)
    Wt[(size_t)(c0 + ty + i) * R + (r0 + tx)] = tile[tx][ty + i];
}

// ---------------- Pipelined 256x256 GEMM (BK=32, 4-slot ring, counted vmcnt) ----
// A  : [M_, K] bf16 row-major
// Bt : [N, K] bf16 (n-major, k-minor)
// GLU=true : combined B rows [a 0-63][g 0-63][a 64-127][g 64-127] per 128-col
//            output block; epilogue writes OutBf = a*sigmoid(g), [M_,2048] bf16.
// GLU=false: plain 256-col output block; epilogue writes OutF fp32 [M_,1024].
//
// Block mapping (cohort-tiled, bijective): XCD j = bid&7 owns bm-stripe
// [8j, 8j+8); bn walked in groups of 4. The ~32 concurrent blocks per XCD
// form an 8bm x 4bn patch -> A-panels shared by 4 blocks, B-panels by 8,
// cutting L2-fill ~3x vs bm-fast ordering.
template<int K, bool GLU>
__global__ __launch_bounds__(512, 2) void k_gemm_pipe(
    const short* __restrict__ A, const short* __restrict__ Bt,
    short* __restrict__ OutBf, float* __restrict__ OutF) {
  extern __shared__ char lds[];
  constexpr int NT = K / 32;
  const int tid = threadIdx.x;
  const int wid = tid >> 6, lane = tid & 63;
  const int l16 = lane & 15, kg = lane >> 4;
  const int wr = wid >> 1, wc = wid & 1;   // 4M x 2N wave grid

  // cohort-tiled XCD mapping (grid = 64*NBN blocks, NBN = 16 or 4)
  const int bid = (int)blockIdx.x;
  const int j = bid & 7;            // XCD
  const int s = bid >> 3;           // sequence within XCD
  const int r = s >> 5;             // bn-group round
  const int t = s & 31;             // position in 8bm x 4bn cohort
  const int bm = j * 8 + (t >> 2);
  const int bn = r * 4 + (t & 3);
  const int m0 = bm * 256;

  // ---- per-thread stage descriptors (2 A-chunks + 2 B-chunks per K-tile) ----
  const short* pA[2];
  const short* pB[2];
  int ldsA[2], ldsB[2];
#pragma unroll
  for (int h = 0; h < 2; ++h) {
    int p = h * 512 + wid * 64 + lane;      // physical 16B chunk this lane fills
    int q = p ^ ((p >> 3) & 7);             // logical chunk (involution)
    int row = q >> 2, c = q & 3;            // 4 chunks per 64B row
    pA[h] = A + (size_t)(m0 + row) * K + c * 8;
    int gb;
    if constexpr (GLU) {
      // combined row -> Bt row: [a c0-63][g c0-63][a c64-127][g c64-127]
      gb = bn * 128 + ((row >> 7) << 6) + (row & 63) + (((row >> 6) & 1) ? 2048 : 0);
    } else {
      gb = bn * 256 + row;
    }
    pB[h] = Bt + (size_t)gb * K + c * 8;
    ldsA[h] = h * 8192 + wid * 1024;            // linear dest, wave-uniform
    ldsB[h] = 16384 + h * 8192 + wid * 1024;
  }

  // ---- ds_read fragment offsets (swizzled, loop-invariant) ----
  int offA[4], offB[8];
#pragma unroll
  for (int m = 0; m < 4; ++m) {
    int row = wr * 64 + m * 16 + l16;
    int ch = row * 4 + kg;
    offA[m] = (ch ^ ((ch >> 3) & 7)) * 16;
  }
#pragma unroll
  for (int n = 0; n < 8; ++n) {
    int row = wc * 128 + n * 16 + l16;
    int ch = row * 4 + kg;
    offB[n] = 16384 + (ch ^ ((ch >> 3) & 7)) * 16;
  }

  const f32x4 z = {0.f, 0.f, 0.f, 0.f};
  f32x4 acc[4][8];
#pragma unroll
  for (int m = 0; m < 4; ++m)
#pragma unroll
    for (int n = 0; n < 8; ++n) acc[m][n] = z;

  // ---- prologue: stage tiles 0..2 (tile-major issue order for vmcnt FIFO) ----
#pragma unroll
  for (int tt = 0; tt < 3; ++tt) {
    char* ws = lds + tt * 32768;
#pragma unroll
    for (int h = 0; h < 2; ++h) {
      gload_lds16(pA[h] + tt * 32, ws + ldsA[h]);
      gload_lds16(pB[h] + tt * 32, ws + ldsB[h]);
    }
  }
#pragma unroll
  for (int h = 0; h < 2; ++h) { pA[h] += 96; pB[h] += 96; }  // -> tile 3

  auto iter = [&](int tt, bool do_stage) {
    __builtin_amdgcn_s_barrier();   // everyone's vmcnt wait done -> tile tt ready
    char* slot = lds + (tt & 3) * 32768;
    char* wsl  = lds + ((tt + 3) & 3) * 32768;
    short8 af[4], bfr[4];
    // ---- phase 0: ds A(4)+B(0..3), stage A of tt+3, MFMA n0..3 ----
#pragma unroll
    for (int m = 0; m < 4; ++m) af[m] = *(const short8*)(slot + offA[m]);
#pragma unroll
    for (int n = 0; n < 4; ++n) bfr[n] = *(const short8*)(slot + offB[n]);
    if (do_stage) {
      gload_lds16(pA[0], wsl + ldsA[0]);
      gload_lds16(pA[1], wsl + ldsA[1]);
    }
    __builtin_amdgcn_s_barrier();
    asm volatile("s_waitcnt lgkmcnt(0)" ::: "memory");
    __builtin_amdgcn_sched_barrier(0);
    __builtin_amdgcn_s_setprio(1);
#pragma unroll
    for (int m = 0; m < 4; ++m)
#pragma unroll
      for (int n = 0; n < 4; ++n)
        acc[m][n] = __builtin_amdgcn_mfma_f32_16x16x32_bf16(af[m], bfr[n], acc[m][n], 0, 0, 0);
    __builtin_amdgcn_s_setprio(0);
    __builtin_amdgcn_s_barrier();
    // ---- phase 1: ds B(4..7), stage B of tt+3, MFMA n4..7 ----
#pragma unroll
    for (int n = 0; n < 4; ++n) bfr[n] = *(const short8*)(slot + offB[4 + n]);
    if (do_stage) {
      gload_lds16(pB[0], wsl + ldsB[0]);
      gload_lds16(pB[1], wsl + ldsB[1]);
      pA[0] += 32; pA[1] += 32; pB[0] += 32; pB[1] += 32;
    }
    __builtin_amdgcn_s_barrier();
    asm volatile("s_waitcnt lgkmcnt(0)" ::: "memory");
    __builtin_amdgcn_sched_barrier(0);
    __builtin_amdgcn_s_setprio(1);
#pragma unroll
    for (int m = 0; m < 4; ++m)
#pragma unroll
      for (int n = 0; n < 4; ++n)
        acc[m][4 + n] = __builtin_amdgcn_mfma_f32_16x16x32_bf16(af[m], bfr[n], acc[m][4 + n], 0, 0, 0);
    __builtin_amdgcn_s_setprio(0);
  };

  // main loop: stages tile t+3, counted vmcnt(8) — never drains to 0
  for (int tt = 0; tt < NT - 3; ++tt) {
    __builtin_amdgcn_s_waitcnt(VMW8);
    iter(tt, true);
  }
  __builtin_amdgcn_s_waitcnt(VMW8); iter(NT - 3, false);
  __builtin_amdgcn_s_waitcnt(VMW4); iter(NT - 2, false);
  __builtin_amdgcn_s_waitcnt(VMW0); iter(NT - 1, false);

  // ---- epilogue (C/D map: col=lane&15, row=(lane>>4)*4+r) ----
  const int r4 = (lane >> 4) * 4;
  if constexpr (GLU) {
#pragma unroll
    for (int m = 0; m < 4; ++m) {
      const int row = m0 + wr * 64 + m * 16 + r4;
#pragma unroll
      for (int n = 0; n < 4; ++n) {
        const int col = bn * 128 + wc * 64 + n * 16 + l16;
#pragma unroll
        for (int rr = 0; rr < 4; ++rr) {
          float a = acc[m][n][rr];
          float g = acc[m][4 + n][rr];
          OutBf[(size_t)(row + rr) * 2048 + col] = f2bfs(a / (1.f + __expf(-g)));
        }
      }
    }
  } else {
#pragma unroll
    for (int m = 0; m < 4; ++m) {
      const int row = m0 + wr * 64 + m * 16 + r4;
#pragma unroll
      for (int n = 0; n < 8; ++n) {
        const int col = bn * 256 + wc * 128 + n * 16 + l16;
#pragma unroll
        for (int rr = 0; rr < 4; ++rr)
          OutF[(size_t)(row + rr) * 1024 + col] = acc[m][n][rr];
      }
    }
  }
}

// ---------------- depthwise causal conv(K=4) + bias + SiLU ----------------
__global__ void k_conv_silu(const short* __restrict__ G, const float* __restrict__ w,
                            const float* __restrict__ bias, short* __restrict__ Y) {
  const int t = threadIdx.x;       // 0..255
  const int c0 = t * 8;            // 8 channels per thread
  const int b = blockIdx.y;
  const int l0 = blockIdx.x * 16;  // 16 rows per thread
  const size_t base = ((size_t)b * L_) * INNER_ + c0;

  float wv[4][8], bv[8];
#pragma unroll
  for (int jj = 0; jj < 8; ++jj) bv[jj] = bias[c0 + jj];
#pragma unroll
  for (int k = 0; k < 4; ++k)
#pragma unroll
    for (int jj = 0; jj < 8; ++jj) wv[k][jj] = w[(c0 + jj) * 4 + k];

  float h[3][8];
#pragma unroll
  for (int p = 0; p < 3; ++p) {
    const int l = l0 - 3 + p;
    if (l < 0) {
#pragma unroll
      for (int jj = 0; jj < 8; ++jj) h[p][jj] = 0.f;
    } else {
      short8 v = *(const short8*)(G + base + (size_t)l * INNER_);
#pragma unroll
      for (int jj = 0; jj < 8; ++jj) h[p][jj] = bfs2f(v[jj]);
    }
  }

  for (int i = 0; i < 16; ++i) {
    const int l = l0 + i;
    short8 v = *(const short8*)(G + base + (size_t)l * INNER_);
    short8 o;
#pragma unroll
    for (int jj = 0; jj < 8; ++jj) {
      float g0 = bfs2f(v[jj]);
      float y = bv[jj] + wv[0][jj] * h[0][jj] + wv[1][jj] * h[1][jj] + wv[2][jj] * h[2][jj] + wv[3][jj] * g0;
      y = y / (1.f + __expf(-y));  // SiLU
      o[jj] = f2bfs(y);
      h[0][jj] = h[1][jj]; h[1][jj] = h[2][jj]; h[2][jj] = g0;
    }
    *(short8*)(Y + base + (size_t)l * INNER_) = o;
  }
}

extern "C" void kernel_launch(void* const* d_in, const int* in_sizes, int n_in,
                              void* d_out, int out_size, void* d_ws, size_t ws_size,
                              hipStream_t stream) {
  (void)in_sizes; (void)n_in; (void)out_size; (void)ws_size;
  const float* x      = (const float*)d_in[0];
  const float* W_in   = (const float*)d_in[1];
  const float* conv_w = (const float*)d_in[2];
  const float* conv_b = (const float*)d_in[3];
  const float* W_out  = (const float*)d_in[4];
  float* out = (float*)d_out;

  char* ws = (char*)d_ws;
  size_t off = 0;
  auto alloc = [&](size_t bytes) {
    char* p = ws + off;
    off += (bytes + 255) & ~(size_t)255;
    return p;
  };
  short* Xb    = (short*)alloc((size_t)M_ * D_ * 2);       // 33.5 MB
  short* WinT  = (short*)alloc((size_t)N1_ * D_ * 2);      // 8.4 MB
  short* WoutT = (short*)alloc((size_t)D_ * INNER_ * 2);   // 4.2 MB
  short* G     = (short*)alloc((size_t)M_ * INNER_ * 2);   // 67 MB
  short* Y     = (short*)alloc((size_t)M_ * INNER_ * 2);   // 67 MB

  // allow 128 KiB dynamic LDS (idempotent; same work every call)
  hipFuncSetAttribute((const void*)k_gemm_pipe<1024, true>,
                      hipFuncAttributeMaxDynamicSharedMemorySize, 131072);
  hipFuncSetAttribute((const void*)k_gemm_pipe<2048, false>,
                      hipFuncAttributeMaxDynamicSharedMemorySize, 131072);

  // Convert x to bf16
  k_cvt<<<(M_ * D_ / 4 + 255) / 256, 256, 0, stream>>>(
      (const float4*)x, (short4*)Xb, M_ * D_ / 4);
  // Transpose+convert weights
  k_transpose_cvt<<<dim3(N1_ / 32, D_ / 32), 256, 0, stream>>>(W_in, WinT, D_, N1_);
  k_transpose_cvt<<<dim3(D_ / 32, INNER_ / 32), 256, 0, stream>>>(W_out, WoutT, INNER_, D_);

  // GEMM1 + GLU -> G   (grid: 64 M-blocks x 16 N-blocks)
  k_gemm_pipe<1024, true><<<1024, 512, 131072, stream>>>(Xb, WinT, G, nullptr);
  // conv + SiLU -> Y
  k_conv_silu<<<dim3(L_ / 16, B_), 256, 0, stream>>>(G, conv_w, conv_b, Y);
  // GEMM2 -> out (fp32)   (grid: 64 x 4)
  k_gemm_pipe<2048, false><<<256, 512, 131072, stream>>>(Y, WoutT, nullptr, out);
}

// Round 5
// 376.682 us; speedup vs baseline: 1.0521x; 1.0034x over previous
//
#include <hip/hip_runtime.h>
#include <hip/hip_bf16.h>

// Problem constants
constexpr int B_ = 4, L_ = 4096, D_ = 1024, INNER_ = 2048;
constexpr int M_ = B_ * L_;       // 16384 rows
constexpr int N1_ = 2 * INNER_;   // 4096 (W_in output cols)

typedef __attribute__((ext_vector_type(4))) float f32x4;
typedef __attribute__((ext_vector_type(16))) float f32x16;
typedef __attribute__((ext_vector_type(8))) short short8;

#define DEV static __device__ __forceinline__

DEV short f2bfs(float f) {
  __hip_bfloat16 h = __float2bfloat16(f);
  return __builtin_bit_cast(short, h);
}
DEV float bfs2f(short s) {
  unsigned int u = ((unsigned int)(unsigned short)s) << 16;
  return __builtin_bit_cast(float, u);
}

DEV void gload_lds16(const void* g, void* l) {
  __builtin_amdgcn_global_load_lds(
      (const __attribute__((address_space(1))) unsigned int*)g,
      (__attribute__((address_space(3))) unsigned int*)l,
      16, 0, 0);
}

// gfx9 s_waitcnt immediates: vmcnt[3:0]|expcnt<<4|lgkmcnt<<8|vmcnt[5:4]<<14
constexpr int VMW8 = 0x0F78;  // vmcnt(8), others no-wait
constexpr int VMW4 = 0x0F74;  // vmcnt(4)
constexpr int VMW0 = 0x0F70;  // vmcnt(0)

// ---------------- fp32 -> bf16 convert (vectorized) ----------------
__global__ void k_cvt(const float4* __restrict__ in, short4* __restrict__ out, int n4) {
  int i = blockIdx.x * blockDim.x + threadIdx.x;
  if (i >= n4) return;
  float4 v = in[i];
  short4 o;
  o.x = f2bfs(v.x); o.y = f2bfs(v.y); o.z = f2bfs(v.z); o.w = f2bfs(v.w);
  out[i] = o;
}

// ---------------- fp32 [R][C] -> bf16 transposed [C][R] ----------------
__global__ void k_transpose_cvt(const float* __restrict__ W, short* __restrict__ Wt,
                                int R, int C) {
  __shared__ short tile[32][33];
  int tx = threadIdx.x & 31;
  int ty = threadIdx.x >> 5;          // 0..7
  int c0 = blockIdx.x * 32;
  int r0 = blockIdx.y * 32;
#pragma unroll
  for (int i = 0; i < 32; i += 8)
    tile[ty + i][tx] = f2bfs(W[(size_t)(r0 + ty + i) * C + (c0 + tx)]);
  __syncthreads();
#pragma unroll
  for (int i = 0; i < 32; i += 8)
    Wt[(size_t)(c0 + ty + i) * R + (r0 + tx)] = tile[tx][ty + i];
}

// ---------------- Pipelined 256x256 GEMM, 32x32x16 MFMA, 1 barrier/K-tile ----
// A  : [M_, K] bf16 row-major
// Bt : [N, K] bf16 (n-major, k-minor)
// GLU=true : combined B rows [a 0-63][g 0-63][a 64-127][g 64-127] per 128-col
//            output block; epilogue writes OutBf = a*sigmoid(g), [M_,2048] bf16.
// GLU=false: plain 256-col output block; epilogue writes OutF fp32 [M_,1024].
//
// Per K-tile: vmcnt(8) -> barrier -> 12 ds_read_b128 + 4 global_load_lds ->
// 16 x mfma_32x32x16 (compiler-interleaved with reads via auto lgkmcnt) ->
// lgkmcnt(0) fence (slot-reuse safety before next barrier).
template<int K, bool GLU>
__global__ __launch_bounds__(512, 2) void k_gemm_pipe(
    const short* __restrict__ A, const short* __restrict__ Bt,
    short* __restrict__ OutBf, float* __restrict__ OutF) {
  extern __shared__ char lds[];
  constexpr int NT = K / 32;
  const int tid = threadIdx.x;
  const int wid = tid >> 6, lane = tid & 63;
  const int l32 = lane & 31, kh = lane >> 5;   // 32x32 frag coords
  const int wr = wid >> 1, wc = wid & 1;       // 4M x 2N wave grid

  // cohort-tiled XCD mapping (grid = 64*NBN blocks): XCD j owns bm-stripe,
  // concurrent blocks form an 8bm x 4bn patch (A-panels shared x4, B x8).
  const int bid = (int)blockIdx.x;
  const int j = bid & 7;
  const int s = bid >> 3;
  const int r = s >> 5;
  const int t = s & 31;
  const int bm = j * 8 + (t >> 2);
  const int bn = r * 4 + (t & 3);
  const int m0 = bm * 256;

  // ---- per-thread stage descriptors (2 A-chunks + 2 B-chunks per K-tile) ----
  const short* pA[2];
  const short* pB[2];
  int ldsA[2], ldsB[2];
#pragma unroll
  for (int h = 0; h < 2; ++h) {
    int p = h * 512 + wid * 64 + lane;      // physical 16B chunk this lane fills
    int q = p ^ ((p >> 3) & 7);             // logical chunk (involution)
    int row = q >> 2, c = q & 3;            // 4 chunks per 64B row
    pA[h] = A + (size_t)(m0 + row) * K + c * 8;
    int gb;
    if constexpr (GLU) {
      gb = bn * 128 + ((row >> 7) << 6) + (row & 63) + (((row >> 6) & 1) ? 2048 : 0);
    } else {
      gb = bn * 256 + row;
    }
    pB[h] = Bt + (size_t)gb * K + c * 8;
    ldsA[h] = h * 8192 + wid * 1024;            // linear dest, wave-uniform
    ldsB[h] = 16384 + h * 8192 + wid * 1024;
  }

  // ---- ds_read fragment offsets (swizzled, loop-invariant) ----
  // A frag (32x16): row = wr*64 + m*32 + l32, k-chunk = ks*2 + kh
  // B frag        : row = wc*128 + n*32 + l32, same k-chunk
  int offA[2][2], offB[4][2];
#pragma unroll
  for (int m = 0; m < 2; ++m)
#pragma unroll
    for (int ks = 0; ks < 2; ++ks) {
      int row = wr * 64 + m * 32 + l32;
      int ch = row * 4 + ks * 2 + kh;
      offA[m][ks] = (ch ^ ((ch >> 3) & 7)) * 16;
    }
#pragma unroll
  for (int n = 0; n < 4; ++n)
#pragma unroll
    for (int ks = 0; ks < 2; ++ks) {
      int row = wc * 128 + n * 32 + l32;
      int ch = row * 4 + ks * 2 + kh;
      offB[n][ks] = 16384 + (ch ^ ((ch >> 3) & 7)) * 16;
    }

  f32x16 acc[2][4];
#pragma unroll
  for (int m = 0; m < 2; ++m)
#pragma unroll
    for (int n = 0; n < 4; ++n)
#pragma unroll
      for (int e = 0; e < 16; ++e) acc[m][n][e] = 0.f;

  // ---- prologue: stage tiles 0..2 (tile-major issue order for vmcnt FIFO) ----
#pragma unroll
  for (int tt = 0; tt < 3; ++tt) {
    char* ws = lds + tt * 32768;
#pragma unroll
    for (int h = 0; h < 2; ++h) {
      gload_lds16(pA[h] + tt * 32, ws + ldsA[h]);
      gload_lds16(pB[h] + tt * 32, ws + ldsB[h]);
    }
  }
#pragma unroll
  for (int h = 0; h < 2; ++h) { pA[h] += 96; pB[h] += 96; }  // -> tile 3

  auto iter = [&](int tt, bool do_stage) {
    __builtin_amdgcn_s_barrier();   // all waves' vmcnt met -> tile tt ready;
                                    // all waves' lgkm0 done -> slot (tt-1) free
    char* slot = lds + (tt & 3) * 32768;
    char* wsl  = lds + ((tt + 3) & 3) * 32768;
    short8 a0[2], a1[2], b0[4], b1[4];
#pragma unroll
    for (int m = 0; m < 2; ++m) a0[m] = *(const short8*)(slot + offA[m][0]);
#pragma unroll
    for (int n = 0; n < 4; ++n) b0[n] = *(const short8*)(slot + offB[n][0]);
    if (do_stage) {
      gload_lds16(pA[0], wsl + ldsA[0]);
      gload_lds16(pA[1], wsl + ldsA[1]);
      gload_lds16(pB[0], wsl + ldsB[0]);
      gload_lds16(pB[1], wsl + ldsB[1]);
      pA[0] += 32; pA[1] += 32; pB[0] += 32; pB[1] += 32;
    }
#pragma unroll
    for (int m = 0; m < 2; ++m) a1[m] = *(const short8*)(slot + offA[m][1]);
#pragma unroll
    for (int n = 0; n < 4; ++n) b1[n] = *(const short8*)(slot + offB[n][1]);
    __builtin_amdgcn_s_setprio(1);
#pragma unroll
    for (int m = 0; m < 2; ++m)
#pragma unroll
      for (int n = 0; n < 4; ++n)
        acc[m][n] = __builtin_amdgcn_mfma_f32_32x32x16_bf16(a0[m], b0[n], acc[m][n], 0, 0, 0);
#pragma unroll
    for (int m = 0; m < 2; ++m)
#pragma unroll
      for (int n = 0; n < 4; ++n)
        acc[m][n] = __builtin_amdgcn_mfma_f32_32x32x16_bf16(a1[m], b1[n], acc[m][n], 0, 0, 0);
    __builtin_amdgcn_s_setprio(0);
    asm volatile("s_waitcnt lgkmcnt(0)" ::: "memory");  // reads drained before
                                                        // next barrier (slot reuse)
  };

  // main loop: stages tile t+3, counted vmcnt(8) — never drains to 0
  for (int tt = 0; tt < NT - 3; ++tt) {
    __builtin_amdgcn_s_waitcnt(VMW8);
    iter(tt, true);
  }
  __builtin_amdgcn_s_waitcnt(VMW8); iter(NT - 3, false);
  __builtin_amdgcn_s_waitcnt(VMW4); iter(NT - 2, false);
  __builtin_amdgcn_s_waitcnt(VMW0); iter(NT - 1, false);

  // ---- epilogue (32x32 C/D map: col=lane&31, row=(reg&3)+8*(reg>>2)+4*kh) ----
  if constexpr (GLU) {
#pragma unroll
    for (int m = 0; m < 2; ++m)
#pragma unroll
      for (int n = 0; n < 2; ++n) {
        const f32x16 Aa = acc[m][n];
        const f32x16 Gg = acc[m][n + 2];
        const int col = bn * 128 + wc * 64 + n * 32 + l32;
#pragma unroll
        for (int reg = 0; reg < 16; ++reg) {
          const int row = m0 + wr * 64 + m * 32 + (reg & 3) + ((reg >> 2) << 3) + (kh << 2);
          OutBf[(size_t)row * 2048 + col] = f2bfs(Aa[reg] / (1.f + __expf(-Gg[reg])));
        }
      }
  } else {
#pragma unroll
    for (int m = 0; m < 2; ++m)
#pragma unroll
      for (int n = 0; n < 4; ++n) {
        const int col = bn * 256 + wc * 128 + n * 32 + l32;
#pragma unroll
        for (int reg = 0; reg < 16; ++reg) {
          const int row = m0 + wr * 64 + m * 32 + (reg & 3) + ((reg >> 2) << 3) + (kh << 2);
          OutF[(size_t)row * 1024 + col] = acc[m][n][reg];
        }
      }
  }
}

// ---------------- depthwise causal conv(K=4) + bias + SiLU ----------------
__global__ void k_conv_silu(const short* __restrict__ G, const float* __restrict__ w,
                            const float* __restrict__ bias, short* __restrict__ Y) {
  const int t = threadIdx.x;       // 0..255
  const int c0 = t * 8;            // 8 channels per thread
  const int b = blockIdx.y;
  const int l0 = blockIdx.x * 16;  // 16 rows per thread
  const size_t base = ((size_t)b * L_) * INNER_ + c0;

  float wv[4][8], bv[8];
#pragma unroll
  for (int jj = 0; jj < 8; ++jj) bv[jj] = bias[c0 + jj];
#pragma unroll
  for (int k = 0; k < 4; ++k)
#pragma unroll
    for (int jj = 0; jj < 8; ++jj) wv[k][jj] = w[(c0 + jj) * 4 + k];

  float h[3][8];
#pragma unroll
  for (int p = 0; p < 3; ++p) {
    const int l = l0 - 3 + p;
    if (l < 0) {
#pragma unroll
      for (int jj = 0; jj < 8; ++jj) h[p][jj] = 0.f;
    } else {
      short8 v = *(const short8*)(G + base + (size_t)l * INNER_);
#pragma unroll
      for (int jj = 0; jj < 8; ++jj) h[p][jj] = bfs2f(v[jj]);
    }
  }

  for (int i = 0; i < 16; ++i) {
    const int l = l0 + i;
    short8 v = *(const short8*)(G + base + (size_t)l * INNER_);
    short8 o;
#pragma unroll
    for (int jj = 0; jj < 8; ++jj) {
      float g0 = bfs2f(v[jj]);
      float y = bv[jj] + wv[0][jj] * h[0][jj] + wv[1][jj] * h[1][jj] + wv[2][jj] * h[2][jj] + wv[3][jj] * g0;
      y = y / (1.f + __expf(-y));  // SiLU
      o[jj] = f2bfs(y);
      h[0][jj] = h[1][jj]; h[1][jj] = h[2][jj]; h[2][jj] = g0;
    }
    *(short8*)(Y + base + (size_t)l * INNER_) = o;
  }
}

extern "C" void kernel_launch(void* const* d_in, const int* in_sizes, int n_in,
                              void* d_out, int out_size, void* d_ws, size_t ws_size,
                              hipStream_t stream) {
  (void)in_sizes; (void)n_in; (void)out_size; (void)ws_size;
  const float* x      = (const float*)d_in[0];
  const float* W_in   = (const float*)d_in[1];
  const float* conv_w = (const float*)d_in[2];
  const float* conv_b = (const float*)d_in[3];
  const float* W_out  = (const float*)d_in[4];
  float* out = (float*)d_out;

  char* ws = (char*)d_ws;
  size_t off = 0;
  auto alloc = [&](size_t bytes) {
    char* p = ws + off;
    off += (bytes + 255) & ~(size_t)255;
    return p;
  };
  short* Xb    = (short*)alloc((size_t)M_ * D_ * 2);       // 33.5 MB
  short* WinT  = (short*)alloc((size_t)N1_ * D_ * 2);      // 8.4 MB
  short* WoutT = (short*)alloc((size_t)D_ * INNER_ * 2);   // 4.2 MB
  short* G     = (short*)alloc((size_t)M_ * INNER_ * 2);   // 67 MB
  short* Y     = (short*)alloc((size_t)M_ * INNER_ * 2);   // 67 MB

  // allow 128 KiB dynamic LDS (idempotent; same work every call)
  hipFuncSetAttribute((const void*)k_gemm_pipe<1024, true>,
                      hipFuncAttributeMaxDynamicSharedMemorySize, 131072);
  hipFuncSetAttribute((const void*)k_gemm_pipe<2048, false>,
                      hipFuncAttributeMaxDynamicSharedMemorySize, 131072);

  // Convert x to bf16
  k_cvt<<<(M_ * D_ / 4 + 255) / 256, 256, 0, stream>>>(
      (const float4*)x, (short4*)Xb, M_ * D_ / 4);
  // Transpose+convert weights
  k_transpose_cvt<<<dim3(N1_ / 32, D_ / 32), 256, 0, stream>>>(W_in, WinT, D_, N1_);
  k_transpose_cvt<<<dim3(D_ / 32, INNER_ / 32), 256, 0, stream>>>(W_out, WoutT, INNER_, D_);

  // GEMM1 + GLU -> G   (grid: 64 M-blocks x 16 N-blocks)
  k_gemm_pipe<1024, true><<<1024, 512, 131072, stream>>>(Xb, WinT, G, nullptr);
  // conv + SiLU -> Y
  k_conv_silu<<<dim3(L_ / 16, B_), 256, 0, stream>>>(G, conv_w, conv_b, Y);
  // GEMM2 -> out (fp32)   (grid: 64 x 4)
  k_gemm_pipe<2048, false><<<256, 512, 131072, stream>>>(Y, WoutT, nullptr, out);
}